// Round 16
// baseline (127.313 us; speedup 1.0000x reference)
//
#include <hip/hip_runtime.h>
#include <hip/hip_bf16.h>
#include <hip/hip_cooperative_groups.h>
#include <math.h>

namespace cg = cooperative_groups;

// Problem constants
#define BB 8
#define SS 1024
#define INDIM 512
#define ED 512
#define NH 8
#define HD 64

typedef __attribute__((ext_vector_type(8))) short short8;
typedef __attribute__((ext_vector_type(4))) float f32x4;
typedef __attribute__((ext_vector_type(16))) float f32x16;
typedef unsigned short u16;

typedef __attribute__((address_space(1))) const void gv_t;
typedef __attribute__((address_space(3))) void lv_t;

static __device__ __forceinline__ u16 f2bf(float f) {
  union { float f; unsigned u; } v; v.f = f;
  unsigned r = v.u + 0x7fffu + ((v.u >> 16) & 1u);
  return (u16)(r >> 16);
}
static __device__ __forceinline__ float bf2f(u16 b) {
  union { unsigned u; float f; } v; v.u = (unsigned)b << 16; return v.f;
}

// packed f32x2 -> bf16x2 (RTNE), single VOP3 instr on gfx950
static __device__ __forceinline__ unsigned cvt_pk_bf16(float a, float b) {
  unsigned r;
  asm("v_cvt_pk_bf16_f32 %0, %1, %2" : "=v"(r) : "v"(a), "v"(b));
  return r;
}
// v_exp_f32 = 2^x natively
static __device__ __forceinline__ float fast_exp2(float x) {
  float r; asm("v_exp_f32 %0, %1" : "=v"(r) : "v"(x)); return r;
}

// ---------------- fp32 -> bf16 convert (all three inputs, one launch) ------
__global__ void cvt_all(const float* __restrict__ x, const float* __restrict__ wq,
                        const float* __restrict__ wo, u16* __restrict__ xb,
                        u16* __restrict__ wqb, u16* __restrict__ wob) {
  const int n1 = 1048576;            // x: 4194304/4 quads
  const int n2 = n1 + 196608;        // wqkv: 786432/4
  const int n3 = n2 + 65536;         // wo: 262144/4
  int i = blockIdx.x * blockDim.x + threadIdx.x;
  int stride = gridDim.x * blockDim.x;
  for (; i < n3; i += stride) {
    const float4* src; ushort4* dst; int j;
    if (i < n1)      { src = (const float4*)x;  dst = (ushort4*)xb;  j = i; }
    else if (i < n2) { src = (const float4*)wq; dst = (ushort4*)wqb; j = i - n1; }
    else             { src = (const float4*)wo; dst = (ushort4*)wob; j = i - n2; }
    float4 v = src[j];
    ushort4 o;
    o.x = f2bf(v.x); o.y = f2bf(v.y); o.z = f2bf(v.z); o.w = f2bf(v.w);
    dst[j] = o;
  }
}

// ---------------- QKV GEMM: C[M,N] = A[M,K] * B[N,K]^T (bf16 in, MFMA) -----
// R15-measured-best: single-buffer 32 KB LDS, global_load_lds width=16 into
// linear [128][64], XOR-swizzled source (c8 ^= row&7) + same XOR on ds_read.
// Epilogue: q/k scalar-contiguous; V chunk transposed through LDS and written
// 16B-coalesced (R15 win: kills ~128 MB of write-sector waste).
__global__ __launch_bounds__(256, 2)
void gemm_qkv(const u16* __restrict__ A, const u16* __restrict__ Bm, int K,
              u16* __restrict__ qws, u16* __restrict__ kws, u16* __restrict__ vtws)
{
  __shared__ u16 As[128][64];
  __shared__ u16 Bs[128][64];
  const int tid = threadIdx.x;
  const int lane = tid & 63;
  const int wv = tid >> 6;
  const int wr = wv >> 1, wc = wv & 1;
  const int bm = blockIdx.x, bn = blockIdx.y;
  const int l15 = lane & 15, lg = lane >> 4;
  const int srow8 = lane >> 3;   // 0..7 within an 8-row staging stripe
  const int sc8 = lane & 7;      // 16B column within row

  f32x4 acc[4][4];
  #pragma unroll
  for (int i = 0; i < 4; i++)
    #pragma unroll
    for (int j = 0; j < 4; j++) acc[i][j] = (f32x4){0.f, 0.f, 0.f, 0.f};

  for (int kk = 0; kk < K; kk += 64) {
    #pragma unroll
    for (int i = 0; i < 4; i++) {
      int r0 = (i * 4 + wv) * 8;
      int r = r0 + srow8;
      int cs = sc8 ^ (r & 7);
      const u16* ga = A + (size_t)(bm * 128 + r) * K + kk + cs * 8;
      __builtin_amdgcn_global_load_lds((gv_t*)ga, (lv_t*)&As[r0][0], 16, 0, 0);
      const u16* gb = Bm + (size_t)(bn * 128 + r) * K + kk + cs * 8;
      __builtin_amdgcn_global_load_lds((gv_t*)gb, (lv_t*)&Bs[r0][0], 16, 0, 0);
    }
    __syncthreads();   // compiler inserts vmcnt(0) drain before barrier
    #pragma unroll
    for (int kc = 0; kc < 2; kc++) {
      short8 af[4], bf[4];
      #pragma unroll
      for (int mi = 0; mi < 4; mi++) {
        int ra = wr * 64 + mi * 16 + l15;
        af[mi] = *(const short8*)&As[ra][((kc * 4 + lg) ^ (ra & 7)) * 8];
      }
      #pragma unroll
      for (int ni = 0; ni < 4; ni++) {
        int rb = wc * 64 + ni * 16 + l15;
        bf[ni] = *(const short8*)&Bs[rb][((kc * 4 + lg) ^ (rb & 7)) * 8];
      }
      #pragma unroll
      for (int mi = 0; mi < 4; mi++)
        #pragma unroll
        for (int ni = 0; ni < 4; ni++)
          acc[mi][ni] = __builtin_amdgcn_mfma_f32_16x16x32_bf16(af[mi], bf[ni], acc[mi][ni], 0, 0, 0);
    }
    __syncthreads();
  }

  // ---- epilogue; C-frag: col = lane&15, row = (lane>>4)*4 + r ----
  #pragma unroll
  for (int mi = 0; mi < 4; mi++) {
    int rowg = bm * 128 + wr * 64 + mi * 16 + lg * 4;
    #pragma unroll
    for (int ni = 0; ni < 4; ni++) {
      int colg = bn * 128 + wc * 64 + ni * 16 + l15;
      int h = colg / 192, c = colg - h * 192;
      #pragma unroll
      for (int r = 0; r < 4; r++) {
        int rg = rowg + r;
        float v = acc[mi][ni][r];
        int b = rg >> 10, s = rg & 1023;
        int bh = b * 8 + h;
        if (c < 64)
          qws[((size_t)(bh * 1024 + s)) * 64 + c] = f2bf(v * 0.18033688f); // 0.125*log2(e)
        else if (c < 128)
          kws[((size_t)(bh * 1024 + s)) * 64 + (c - 64)] = f2bf(v);
        // c >= 128 (V) handled below via LDS transpose
      }
    }
  }
  // V chunk: window-local cols [vbase, vbase+64) iff rem != 0
  const int rem = (bn * 128) % 192;
  if (rem != 0) {
    __shared__ u16 T[64][136];     // 64 cols x 128 rows (+pad), 16B-aligned stride
    const int vbase = (rem == 128) ? 0 : 64;
    if (wc == (vbase >> 6)) {
      #pragma unroll
      for (int mi = 0; mi < 4; mi++) {
        int trow0 = wr * 64 + mi * 16 + lg * 4;
        #pragma unroll
        for (int ni = 0; ni < 4; ni++) {
          int tcol = ni * 16 + l15;
          u16 tmp[4];
          #pragma unroll
          for (int r = 0; r < 4; r++) tmp[r] = f2bf(acc[mi][ni][r]);
          *(uint2*)&T[tcol][trow0] = *(const uint2*)tmp;
        }
      }
    }
    __syncthreads();
    // coalesced write-out: vt[bh*64 + col][ (bm&7)*128 + row ]
    const int h = (bn * 128 + vbase) / 192;
    const int bh = (bm >> 3) * 8 + h;
    const int col = tid >> 2, q4 = tid & 3;
    u16* dst = vtws + ((size_t)(bh * 64 + col)) * 1024 + (bm & 7) * 128 + q4 * 32;
    const u16* src = &T[col][q4 * 32];
    #pragma unroll
    for (int k2 = 0; k2 < 4; k2++)
      *(uint4*)(dst + k2 * 8) = *(const uint4*)(src + k2 * 8);
  }
}

// -------- O-projection + FUSED LayerNorm (cooperative grid sync) -----------
// grid (64,4) = 256 blocks <= 256 CUs -> all co-resident. Each block:
// GEMM -> publish per-block (sum, sumsq) -> grid.sync() -> re-reduce this
// batch's 32 partials (256 B) -> write normalized fp32 straight from the
// fp32 accumulators. Removes the 16 MB outb write + 16 MB read + 1 launch.
__global__ __launch_bounds__(256, 2)
void gemm_o_ln(const u16* __restrict__ A, const u16* __restrict__ Bm,
               float* __restrict__ outF, float2* __restrict__ partials)
{
  __shared__ u16 As[128][64];
  __shared__ u16 Bs[128][64];
  const int K = 512;
  const int tid = threadIdx.x;
  const int lane = tid & 63;
  const int wv = tid >> 6;
  const int wr = wv >> 1, wc = wv & 1;
  const int bm = blockIdx.x, bn = blockIdx.y;
  const int l15 = lane & 15, lg = lane >> 4;
  const int srow8 = lane >> 3;
  const int sc8 = lane & 7;

  f32x4 acc[4][4];
  #pragma unroll
  for (int i = 0; i < 4; i++)
    #pragma unroll
    for (int j = 0; j < 4; j++) acc[i][j] = (f32x4){0.f, 0.f, 0.f, 0.f};

  for (int kk = 0; kk < K; kk += 64) {
    #pragma unroll
    for (int i = 0; i < 4; i++) {
      int r0 = (i * 4 + wv) * 8;
      int r = r0 + srow8;
      int cs = sc8 ^ (r & 7);
      const u16* ga = A + (size_t)(bm * 128 + r) * K + kk + cs * 8;
      __builtin_amdgcn_global_load_lds((gv_t*)ga, (lv_t*)&As[r0][0], 16, 0, 0);
      const u16* gb = Bm + (size_t)(bn * 128 + r) * K + kk + cs * 8;
      __builtin_amdgcn_global_load_lds((gv_t*)gb, (lv_t*)&Bs[r0][0], 16, 0, 0);
    }
    __syncthreads();
    #pragma unroll
    for (int kc = 0; kc < 2; kc++) {
      short8 af[4], bf[4];
      #pragma unroll
      for (int mi = 0; mi < 4; mi++) {
        int ra = wr * 64 + mi * 16 + l15;
        af[mi] = *(const short8*)&As[ra][((kc * 4 + lg) ^ (ra & 7)) * 8];
      }
      #pragma unroll
      for (int ni = 0; ni < 4; ni++) {
        int rb = wc * 64 + ni * 16 + l15;
        bf[ni] = *(const short8*)&Bs[rb][((kc * 4 + lg) ^ (rb & 7)) * 8];
      }
      #pragma unroll
      for (int mi = 0; mi < 4; mi++)
        #pragma unroll
        for (int ni = 0; ni < 4; ni++)
          acc[mi][ni] = __builtin_amdgcn_mfma_f32_16x16x32_bf16(af[mi], bf[ni], acc[mi][ni], 0, 0, 0);
    }
    __syncthreads();
  }

  // ---- per-block LN partials from fp32 accumulators ----
  float s1 = 0.f, s2 = 0.f;
  #pragma unroll
  for (int mi = 0; mi < 4; mi++)
    #pragma unroll
    for (int ni = 0; ni < 4; ni++)
      #pragma unroll
      for (int r = 0; r < 4; r++) {
        float v = acc[mi][ni][r];
        s1 += v; s2 += v * v;
      }
  #pragma unroll
  for (int off = 1; off < 64; off <<= 1) {
    s1 += __shfl_xor(s1, off);
    s2 += __shfl_xor(s2, off);
  }
  __shared__ float r1[4], r2[4];
  if (lane == 0) { r1[wv] = s1; r2[wv] = s2; }
  __syncthreads();
  if (tid == 0) {
    float t1 = r1[0] + r1[1] + r1[2] + r1[3];
    float t2 = r2[0] + r2[1] + r2[2] + r2[3];
    partials[bm * 4 + bn] = make_float2(t1, t2);
    __threadfence();
  }

  cg::this_grid().sync();

  // ---- re-reduce this batch's 32 partials (256 B, L2-broadcast) ----
  float a = 0.f, c = 0.f;
  if (lane < 32) {
    float2 p = partials[(bm >> 3) * 32 + lane];
    a = p.x; c = p.y;
  }
  #pragma unroll
  for (int off = 1; off < 64; off <<= 1) {
    a += __shfl_xor(a, off);
    c += __shfl_xor(c, off);
  }
  float mu = a / 524288.f;
  float rs = rsqrtf(c / 524288.f - mu * mu + 1e-5f);

  // ---- normalized fp32 write straight from accumulators ----
  #pragma unroll
  for (int mi = 0; mi < 4; mi++) {
    int rowg = bm * 128 + wr * 64 + mi * 16 + lg * 4;
    #pragma unroll
    for (int ni = 0; ni < 4; ni++) {
      int colg = bn * 128 + wc * 64 + ni * 16 + l15;
      #pragma unroll
      for (int r = 0; r < 4; r++)
        outF[(size_t)(rowg + r) * 512 + colg] = (acc[mi][ni][r] - mu) * rs;
    }
  }
}

// ---------------- Flash attention, 32x32 swapped-QK^T, register-only P -----
// (R7/R12/R13/R15 measured-best.) 256 blocks = 64 bh * 4 q-tiles of 256 rows
// (XCD-swizzled: one bh per XCD). 8 waves * 32 q rows share one K/V dbuf.
// Logits in log2 units (Q pre-scaled by 0.125*log2e).
__global__ __launch_bounds__(512, 4)
void attn_kernel(const u16* __restrict__ qws, const u16* __restrict__ kws,
                 const u16* __restrict__ vtws, u16* __restrict__ vals)
{
  __shared__ __align__(16) u16 Ksm[2][64][72];   // K tile [k][d], dbuf
  __shared__ __align__(16) u16 Vsm[2][64][72];   // V tile [d][k], dbuf
  const int tid = threadIdx.x;
  const int lane = tid & 63;
  const int wq = tid >> 6;          // wave id 0..7, 32 q rows each
  const int l31 = lane & 31;
  const int hi = lane >> 5;
  // XCD swizzle: 256 blocks -> 32 consecutive logical blocks per XCD
  const int logical = (blockIdx.x & 7) * 32 + (blockIdx.x >> 3);
  const int bh = logical >> 2;
  const int q0 = (logical & 3) * 256;

  // ---- Q B-frags from global: col=q=l31, k-dim d = 16j+8hi+e ----
  short8 qf[4];
  {
    const u16* qp = qws + ((size_t)bh * 1024 + q0 + wq * 32 + l31) * 64 + 8 * hi;
    #pragma unroll
    for (int j = 0; j < 4; j++) qf[j] = *(const short8*)(qp + 16 * j);
  }

  // ---- stage K/V tile 0 (512 threads: one uint4 each per tile) ----
  const int srow = tid >> 3;             // 0..63
  const int sc8 = (tid & 7) * 8;
  uint4 kreg, vreg;
  kreg = *(const uint4*)(kws + ((size_t)bh * 1024 + srow) * 64 + sc8);
  vreg = *(const uint4*)(vtws + ((size_t)(bh * 64 + srow)) * 1024 + sc8);
  *(uint4*)&Ksm[0][srow][sc8] = kreg;
  *(uint4*)&Vsm[0][srow][sc8] = vreg;
  __syncthreads();

  f32x16 o[2];
  #pragma unroll
  for (int r = 0; r < 16; r++) { o[0][r] = 0.f; o[1][r] = 0.f; }
  float m = -1e30f, l = 0.f;

  for (int t = 0; t < 16; t++) {
    const int cur = t & 1;
    // T14: issue next-tile global loads first (latency hides under compute)
    if (t < 15) {
      int kv = (t + 1) * 64;
      kreg = *(const uint4*)(kws + ((size_t)bh * 1024 + kv + srow) * 64 + sc8);
      vreg = *(const uint4*)(vtws + ((size_t)(bh * 64 + srow)) * 1024 + kv + sc8);
    }

    // ---- S^T = K * Q^T: C[row=k_local][col=q=l31] per 32-key subtile ----
    f32x16 stv[2];
    __builtin_amdgcn_s_setprio(1);
    #pragma unroll
    for (int s2 = 0; s2 < 2; s2++) {
      f32x16 c;
      #pragma unroll
      for (int r = 0; r < 16; r++) c[r] = 0.f;
      #pragma unroll
      for (int j = 0; j < 4; j++) {
        short8 kf = *(const short8*)&Ksm[cur][s2 * 32 + l31][16 * j + 8 * hi];
        c = __builtin_amdgcn_mfma_f32_32x32x16_bf16(kf, qf[j], c, 0, 0, 0);
      }
      stv[s2] = c;
    }
    __builtin_amdgcn_s_setprio(0);

    // ---- online softmax: lane owns q=l31, 32 of 64 k's (other half at lane^32)
    float mx[16];
    #pragma unroll
    for (int r = 0; r < 16; r++) mx[r] = fmaxf(stv[0][r], stv[1][r]);
    #pragma unroll
    for (int w = 8; w >= 1; w >>= 1)
      #pragma unroll
      for (int r = 0; r < w; r++) mx[r] = fmaxf(mx[r], mx[r + w]);
    float pm = fmaxf(mx[0], __shfl_xor(mx[0], 32));

    // T13 defer-max (log2 units)
    if (!__all(pm - m <= 10.0f)) {
      float mn = fmaxf(m, pm);
      float al = fast_exp2(m - mn);
      m = mn; l *= al;
      #pragma unroll
      for (int reg = 0; reg < 16; reg++) {
        int qrow = (reg & 3) + 8 * (reg >> 2) + 4 * hi;
        float alo = __shfl(al, qrow);
        o[0][reg] *= alo; o[1][reg] *= alo;
      }
    }

    unsigned pk[16];
    float ps[16];
    #pragma unroll
    for (int s2 = 0; s2 < 2; s2++)
      #pragma unroll
      for (int j = 0; j < 8; j++) {
        float p0 = fast_exp2(stv[s2][2 * j] - m);
        float p1 = fast_exp2(stv[s2][2 * j + 1] - m);
        ps[s2 * 8 + j] = p0 + p1;
        pk[s2 * 8 + j] = cvt_pk_bf16(p0, p1);
      }
    #pragma unroll
    for (int w = 8; w >= 1; w >>= 1)
      #pragma unroll
      for (int r = 0; r < w; r++) ps[r] += ps[r + w];
    l += ps[0] + __shfl_xor(ps[0], 32);

    // ---- P redistribution: 8 permlane32_swap build PV A-frags in-register ----
    short8 pa[4];
    #pragma unroll
    for (int cc = 0; cc < 4; cc++) {
      int base = (cc >> 1) * 8 + (cc & 1) * 4;
      unsigned a0 = pk[base + 0], a2 = pk[base + 2];
      unsigned a1 = pk[base + 1], a3 = pk[base + 3];
      asm volatile("v_permlane32_swap_b32 %0, %1" : "+v"(a0), "+v"(a2));
      asm volatile("v_permlane32_swap_b32 %0, %1" : "+v"(a1), "+v"(a3));
      union { unsigned u[4]; short8 s8; } uu;
      uu.u[0] = a0; uu.u[1] = a1; uu.u[2] = a2; uu.u[3] = a3;
      pa[cc] = uu.s8;
    }

    // ---- O += P * V : A=P[q][k], B=V[k][d] (from Vt rows) ----
    __builtin_amdgcn_s_setprio(1);
    #pragma unroll
    for (int dh = 0; dh < 2; dh++)
      #pragma unroll
      for (int cc = 0; cc < 4; cc++) {
        short8 vf = *(const short8*)&Vsm[cur][dh * 32 + l31][16 * cc + 8 * hi];
        o[dh] = __builtin_amdgcn_mfma_f32_32x32x16_bf16(pa[cc], vf, o[dh], 0, 0, 0);
      }
    __builtin_amdgcn_s_setprio(0);

    // ---- write next tile into other buffer ----
    if (t < 15) {
      *(uint4*)&Ksm[cur ^ 1][srow][sc8] = kreg;
      *(uint4*)&Vsm[cur ^ 1][srow][sc8] = vreg;
    }
    __syncthreads();
  }

  // ---- epilogue: vals[b, s, h*64+d] bf16 ----
  const int b = bh >> 3, h = bh & 7;
  #pragma unroll
  for (int reg = 0; reg < 16; reg++) {
    int qrow = (reg & 3) + 8 * (reg >> 2) + 4 * hi;
    float linv = 1.0f / __shfl(l, qrow);
    size_t grow = (size_t)(b * 1024 + q0 + wq * 32 + qrow) * 512 + h * 64;
    vals[grow + l31]      = f2bf(o[0][reg] * linv);
    vals[grow + 32 + l31] = f2bf(o[1][reg] * linv);
  }
}

extern "C" void kernel_launch(void* const* d_in, const int* in_sizes, int n_in,
                              void* d_out, int out_size, void* d_ws, size_t ws_size,
                              hipStream_t stream) {
  const float* x = (const float*)d_in[0];
  const float* wqkv = (const float*)d_in[1];
  const float* wo = (const float*)d_in[2];
  float* out = (float*)d_out;
  char* ws = (char*)d_ws;

  u16* xb        = (u16*)(ws + 0);          // 8192*512   bf16 =  8,388,608 B
  u16* wqb       = (u16*)(ws + 8388608);    // 1536*512   bf16 =  1,572,864 B
  u16* wob       = (u16*)(ws + 9961472);    // 512*512    bf16 =    524,288 B
  u16* qws       = (u16*)(ws + 10485760);   // [bh,1024,64]    =  8,388,608 B
  u16* kws       = (u16*)(ws + 18874368);   // [bh,1024,64]    =  8,388,608 B
  u16* vtws      = (u16*)(ws + 27262976);   // [bh,64,1024]    =  8,388,608 B
  u16* vals      = (u16*)(ws + 35651584);   // [8192,512] bf16 =  8,388,608 B
  float2* parts  = (float2*)(ws + 44040192);// 256 float2 = 2 KB

  cvt_all<<<1280, 256, 0, stream>>>(x, wqkv, wo, xb, wqb, wob);

  dim3 g1(64, 12);
  gemm_qkv<<<g1, 256, 0, stream>>>(xb, wqb, 512, qws, kws, vtws);

  attn_kernel<<<256, 512, 0, stream>>>(qws, kws, vtws, vals);

  // cooperative O-projection + LayerNorm (grid-wide sync; 256 blocks co-resident)
  {
    const u16* a = vals;
    const u16* b = wob;
    float* o = out;
    float2* p = parts;
    void* args[] = {(void*)&a, (void*)&b, (void*)&o, (void*)&p};
    hipLaunchCooperativeKernel((void*)gemm_o_ln, dim3(64, 4), dim3(256),
                               args, 0, stream);
  }
}

// Round 17
// 76.082 us; speedup vs baseline: 1.6734x; 1.6734x over previous
//
#include <hip/hip_runtime.h>
#include <hip/hip_bf16.h>
#include <math.h>

// Problem constants
#define BB 8
#define SS 1024
#define INDIM 512
#define ED 512
#define NH 8
#define HD 64

typedef __attribute__((ext_vector_type(8))) short short8;
typedef __attribute__((ext_vector_type(4))) float f32x4;
typedef __attribute__((ext_vector_type(16))) float f32x16;
typedef unsigned short u16;

typedef __attribute__((address_space(1))) const void gv_t;
typedef __attribute__((address_space(3))) void lv_t;

static __device__ __forceinline__ u16 f2bf(float f) {
  union { float f; unsigned u; } v; v.f = f;
  unsigned r = v.u + 0x7fffu + ((v.u >> 16) & 1u);
  return (u16)(r >> 16);
}
static __device__ __forceinline__ float bf2f(u16 b) {
  union { unsigned u; float f; } v; v.u = (unsigned)b << 16; return v.f;
}

// packed f32x2 -> bf16x2 (RTNE), single VOP3 instr on gfx950
static __device__ __forceinline__ unsigned cvt_pk_bf16(float a, float b) {
  unsigned r;
  asm("v_cvt_pk_bf16_f32 %0, %1, %2" : "=v"(r) : "v"(a), "v"(b));
  return r;
}
// v_exp_f32 = 2^x natively
static __device__ __forceinline__ float fast_exp2(float x) {
  float r; asm("v_exp_f32 %0, %1" : "=v"(r) : "v"(x)); return r;
}

// ---------------- fp32 -> bf16 convert (all three inputs, one launch) ------
__global__ void cvt_all(const float* __restrict__ x, const float* __restrict__ wq,
                        const float* __restrict__ wo, u16* __restrict__ xb,
                        u16* __restrict__ wqb, u16* __restrict__ wob) {
  const int n1 = 1048576;            // x: 4194304/4 quads
  const int n2 = n1 + 196608;        // wqkv: 786432/4
  const int n3 = n2 + 65536;         // wo: 262144/4
  int i = blockIdx.x * blockDim.x + threadIdx.x;
  int stride = gridDim.x * blockDim.x;
  for (; i < n3; i += stride) {
    const float4* src; ushort4* dst; int j;
    if (i < n1)      { src = (const float4*)x;  dst = (ushort4*)xb;  j = i; }
    else if (i < n2) { src = (const float4*)wq; dst = (ushort4*)wqb; j = i - n1; }
    else             { src = (const float4*)wo; dst = (ushort4*)wob; j = i - n2; }
    float4 v = src[j];
    ushort4 o;
    o.x = f2bf(v.x); o.y = f2bf(v.y); o.z = f2bf(v.z); o.w = f2bf(v.w);
    dst[j] = o;
  }
}

// ---------------- NT GEMM: C[M,N] = A[M,K] * B[N,K]^T (bf16 in, MFMA) -------
// R13-measured-best core: single-buffer 32 KB LDS, global_load_lds width=16
// into linear [128][64], XOR-swizzled source (c8 ^= row&7) + same XOR on
// ds_read (both-sides-or-neither rule).
// EPI==0: QKV epilogue. q/k written scalar-contiguous. The V portion (a
//   single contiguous 64-col x 128-row chunk per block, or none) is
//   TRANSPOSED THROUGH LDS and written 16B-coalesced (R15 win).
// EPI==1: O projection, bf16 out + per-block LN partials (no sync).
template<int EPI>
__global__ __launch_bounds__(256, 2)
void gemm_nt(const u16* __restrict__ A, const u16* __restrict__ Bm, int K,
             u16* __restrict__ outB,
             u16* __restrict__ qws, u16* __restrict__ kws, u16* __restrict__ vtws,
             float2* __restrict__ partials)
{
  __shared__ u16 As[128][64];
  __shared__ u16 Bs[128][64];
  const int tid = threadIdx.x;
  const int lane = tid & 63;
  const int wv = tid >> 6;
  const int wr = wv >> 1, wc = wv & 1;
  const int bm = blockIdx.x, bn = blockIdx.y;
  const int l15 = lane & 15, lg = lane >> 4;
  const int srow8 = lane >> 3;   // 0..7 within an 8-row staging stripe
  const int sc8 = lane & 7;      // 16B column within row

  f32x4 acc[4][4];
  #pragma unroll
  for (int i = 0; i < 4; i++)
    #pragma unroll
    for (int j = 0; j < 4; j++) acc[i][j] = (f32x4){0.f, 0.f, 0.f, 0.f};

  for (int kk = 0; kk < K; kk += 64) {
    // ---- async stage A/B tiles: 4 issues/wave each, 1KB per wave-issue ----
    #pragma unroll
    for (int i = 0; i < 4; i++) {
      int r0 = (i * 4 + wv) * 8;
      int r = r0 + srow8;
      int cs = sc8 ^ (r & 7);
      const u16* ga = A + (size_t)(bm * 128 + r) * K + kk + cs * 8;
      __builtin_amdgcn_global_load_lds((gv_t*)ga, (lv_t*)&As[r0][0], 16, 0, 0);
      const u16* gb = Bm + (size_t)(bn * 128 + r) * K + kk + cs * 8;
      __builtin_amdgcn_global_load_lds((gv_t*)gb, (lv_t*)&Bs[r0][0], 16, 0, 0);
    }
    __syncthreads();   // compiler inserts vmcnt(0) drain before barrier
    #pragma unroll
    for (int kc = 0; kc < 2; kc++) {
      short8 af[4], bf[4];
      #pragma unroll
      for (int mi = 0; mi < 4; mi++) {
        int ra = wr * 64 + mi * 16 + l15;
        af[mi] = *(const short8*)&As[ra][((kc * 4 + lg) ^ (ra & 7)) * 8];
      }
      #pragma unroll
      for (int ni = 0; ni < 4; ni++) {
        int rb = wc * 64 + ni * 16 + l15;
        bf[ni] = *(const short8*)&Bs[rb][((kc * 4 + lg) ^ (rb & 7)) * 8];
      }
      #pragma unroll
      for (int mi = 0; mi < 4; mi++)
        #pragma unroll
        for (int ni = 0; ni < 4; ni++)
          acc[mi][ni] = __builtin_amdgcn_mfma_f32_16x16x32_bf16(af[mi], bf[ni], acc[mi][ni], 0, 0, 0);
    }
    __syncthreads();
  }

  // ---- epilogue; C-frag: col = lane&15, row = (lane>>4)*4 + r ----
  if constexpr (EPI == 0) {
    // q/k scalar writes (contiguous in c across lanes)
    #pragma unroll
    for (int mi = 0; mi < 4; mi++) {
      int rowg = bm * 128 + wr * 64 + mi * 16 + lg * 4;
      #pragma unroll
      for (int ni = 0; ni < 4; ni++) {
        int colg = bn * 128 + wc * 64 + ni * 16 + l15;
        int h = colg / 192, c = colg - h * 192;
        #pragma unroll
        for (int r = 0; r < 4; r++) {
          int rg = rowg + r;
          float v = acc[mi][ni][r];
          int b = rg >> 10, s = rg & 1023;
          int bh = b * 8 + h;
          if (c < 64)
            qws[((size_t)(bh * 1024 + s)) * 64 + c] = f2bf(v * 0.18033688f); // 0.125*log2(e)
          else if (c < 128)
            kws[((size_t)(bh * 1024 + s)) * 64 + (c - 64)] = f2bf(v);
          // c >= 128 (V) handled below via LDS transpose
        }
      }
    }
    // V chunk: window-local cols [vbase, vbase+64) iff rem != 0
    const int rem = (bn * 128) % 192;
    if (rem != 0) {
      __shared__ u16 T[64][136];     // 64 cols x 128 rows (+pad), 16B-aligned stride
      const int vbase = (rem == 128) ? 0 : 64;
      if (wc == (vbase >> 6)) {
        #pragma unroll
        for (int mi = 0; mi < 4; mi++) {
          int trow0 = wr * 64 + mi * 16 + lg * 4;
          #pragma unroll
          for (int ni = 0; ni < 4; ni++) {
            int tcol = ni * 16 + l15;
            u16 tmp[4];
            #pragma unroll
            for (int r = 0; r < 4; r++) tmp[r] = f2bf(acc[mi][ni][r]);
            *(uint2*)&T[tcol][trow0] = *(const uint2*)tmp;
          }
        }
      }
      __syncthreads();
      // coalesced write-out: vt[bh*64 + col][ (bm&7)*128 + row ]
      const int h = (bn * 128 + vbase) / 192;
      const int bh = (bm >> 3) * 8 + h;
      const int col = tid >> 2, q4 = tid & 3;
      u16* dst = vtws + ((size_t)(bh * 64 + col)) * 1024 + (bm & 7) * 128 + q4 * 32;
      const u16* src = &T[col][q4 * 32];
      #pragma unroll
      for (int k2 = 0; k2 < 4; k2++)
        *(uint4*)(dst + k2 * 8) = *(const uint4*)(src + k2 * 8);
    }
  } else {
    // bf16 output write + per-block LN partials from fp32 accumulators
    float s1 = 0.f, s2 = 0.f;
    #pragma unroll
    for (int mi = 0; mi < 4; mi++) {
      int rowg = bm * 128 + wr * 64 + mi * 16 + lg * 4;
      #pragma unroll
      for (int ni = 0; ni < 4; ni++) {
        int colg = bn * 128 + wc * 64 + ni * 16 + l15;
        #pragma unroll
        for (int r = 0; r < 4; r++) {
          float v = acc[mi][ni][r];
          s1 += v; s2 += v * v;
          outB[(size_t)(rowg + r) * 512 + colg] = f2bf(v);
        }
      }
    }
    #pragma unroll
    for (int off = 1; off < 64; off <<= 1) {
      s1 += __shfl_xor(s1, off);
      s2 += __shfl_xor(s2, off);
    }
    __shared__ float r1[4], r2[4];
    if (lane == 0) { r1[wv] = s1; r2[wv] = s2; }
    __syncthreads();
    if (tid == 0) {
      float t1 = r1[0] + r1[1] + r1[2] + r1[3];
      float t2 = r2[0] + r2[1] + r2[2] + r2[3];
      partials[bm * 4 + bn] = make_float2(t1, t2);
    }
  }
}

// ---------------- Flash attention, 32x32 swapped-QK^T, register-only P -----
// (R7/R12/R13/R15 measured-best.) 256 blocks = 64 bh * 4 q-tiles of 256 rows
// (XCD-swizzled: one bh per XCD). 8 waves * 32 q rows share one K/V dbuf.
// Logits in log2 units (Q pre-scaled by 0.125*log2e).
__global__ __launch_bounds__(512, 4)
void attn_kernel(const u16* __restrict__ qws, const u16* __restrict__ kws,
                 const u16* __restrict__ vtws, u16* __restrict__ vals)
{
  __shared__ __align__(16) u16 Ksm[2][64][72];   // K tile [k][d], dbuf
  __shared__ __align__(16) u16 Vsm[2][64][72];   // V tile [d][k], dbuf
  const int tid = threadIdx.x;
  const int lane = tid & 63;
  const int wq = tid >> 6;          // wave id 0..7, 32 q rows each
  const int l31 = lane & 31;
  const int hi = lane >> 5;
  // XCD swizzle: 256 blocks -> 32 consecutive logical blocks per XCD
  const int logical = (blockIdx.x & 7) * 32 + (blockIdx.x >> 3);
  const int bh = logical >> 2;
  const int q0 = (logical & 3) * 256;

  // ---- Q B-frags from global: col=q=l31, k-dim d = 16j+8hi+e ----
  short8 qf[4];
  {
    const u16* qp = qws + ((size_t)bh * 1024 + q0 + wq * 32 + l31) * 64 + 8 * hi;
    #pragma unroll
    for (int j = 0; j < 4; j++) qf[j] = *(const short8*)(qp + 16 * j);
  }

  // ---- stage K/V tile 0 (512 threads: one uint4 each per tile) ----
  const int srow = tid >> 3;             // 0..63
  const int sc8 = (tid & 7) * 8;
  uint4 kreg, vreg;
  kreg = *(const uint4*)(kws + ((size_t)bh * 1024 + srow) * 64 + sc8);
  vreg = *(const uint4*)(vtws + ((size_t)(bh * 64 + srow)) * 1024 + sc8);
  *(uint4*)&Ksm[0][srow][sc8] = kreg;
  *(uint4*)&Vsm[0][srow][sc8] = vreg;
  __syncthreads();

  f32x16 o[2];
  #pragma unroll
  for (int r = 0; r < 16; r++) { o[0][r] = 0.f; o[1][r] = 0.f; }
  float m = -1e30f, l = 0.f;

  for (int t = 0; t < 16; t++) {
    const int cur = t & 1;
    // T14: issue next-tile global loads first (latency hides under compute)
    if (t < 15) {
      int kv = (t + 1) * 64;
      kreg = *(const uint4*)(kws + ((size_t)bh * 1024 + kv + srow) * 64 + sc8);
      vreg = *(const uint4*)(vtws + ((size_t)(bh * 64 + srow)) * 1024 + kv + sc8);
    }

    // ---- S^T = K * Q^T: C[row=k_local][col=q=l31] per 32-key subtile ----
    f32x16 stv[2];
    __builtin_amdgcn_s_setprio(1);
    #pragma unroll
    for (int s2 = 0; s2 < 2; s2++) {
      f32x16 c;
      #pragma unroll
      for (int r = 0; r < 16; r++) c[r] = 0.f;
      #pragma unroll
      for (int j = 0; j < 4; j++) {
        short8 kf = *(const short8*)&Ksm[cur][s2 * 32 + l31][16 * j + 8 * hi];
        c = __builtin_amdgcn_mfma_f32_32x32x16_bf16(kf, qf[j], c, 0, 0, 0);
      }
      stv[s2] = c;
    }
    __builtin_amdgcn_s_setprio(0);

    // ---- online softmax: lane owns q=l31, 32 of 64 k's (other half at lane^32)
    float mx[16];
    #pragma unroll
    for (int r = 0; r < 16; r++) mx[r] = fmaxf(stv[0][r], stv[1][r]);
    #pragma unroll
    for (int w = 8; w >= 1; w >>= 1)
      #pragma unroll
      for (int r = 0; r < w; r++) mx[r] = fmaxf(mx[r], mx[r + w]);
    float pm = fmaxf(mx[0], __shfl_xor(mx[0], 32));

    // T13 defer-max (log2 units)
    if (!__all(pm - m <= 10.0f)) {
      float mn = fmaxf(m, pm);
      float al = fast_exp2(m - mn);
      m = mn; l *= al;
      #pragma unroll
      for (int reg = 0; reg < 16; reg++) {
        int qrow = (reg & 3) + 8 * (reg >> 2) + 4 * hi;
        float alo = __shfl(al, qrow);
        o[0][reg] *= alo; o[1][reg] *= alo;
      }
    }

    unsigned pk[16];
    float ps[16];
    #pragma unroll
    for (int s2 = 0; s2 < 2; s2++)
      #pragma unroll
      for (int j = 0; j < 8; j++) {
        float p0 = fast_exp2(stv[s2][2 * j] - m);
        float p1 = fast_exp2(stv[s2][2 * j + 1] - m);
        ps[s2 * 8 + j] = p0 + p1;
        pk[s2 * 8 + j] = cvt_pk_bf16(p0, p1);
      }
    #pragma unroll
    for (int w = 8; w >= 1; w >>= 1)
      #pragma unroll
      for (int r = 0; r < w; r++) ps[r] += ps[r + w];
    l += ps[0] + __shfl_xor(ps[0], 32);

    // ---- P redistribution: 8 permlane32_swap build PV A-frags in-register ----
    short8 pa[4];
    #pragma unroll
    for (int cc = 0; cc < 4; cc++) {
      int base = (cc >> 1) * 8 + (cc & 1) * 4;
      unsigned a0 = pk[base + 0], a2 = pk[base + 2];
      unsigned a1 = pk[base + 1], a3 = pk[base + 3];
      asm volatile("v_permlane32_swap_b32 %0, %1" : "+v"(a0), "+v"(a2));
      asm volatile("v_permlane32_swap_b32 %0, %1" : "+v"(a1), "+v"(a3));
      union { unsigned u[4]; short8 s8; } uu;
      uu.u[0] = a0; uu.u[1] = a1; uu.u[2] = a2; uu.u[3] = a3;
      pa[cc] = uu.s8;
    }

    // ---- O += P * V : A=P[q][k], B=V[k][d] (from Vt rows) ----
    __builtin_amdgcn_s_setprio(1);
    #pragma unroll
    for (int dh = 0; dh < 2; dh++)
      #pragma unroll
      for (int cc = 0; cc < 4; cc++) {
        short8 vf = *(const short8*)&Vsm[cur][dh * 32 + l31][16 * cc + 8 * hi];
        o[dh] = __builtin_amdgcn_mfma_f32_32x32x16_bf16(pa[cc], vf, o[dh], 0, 0, 0);
      }
    __builtin_amdgcn_s_setprio(0);

    // ---- write next tile into other buffer ----
    if (t < 15) {
      *(uint4*)&Ksm[cur ^ 1][srow][sc8] = kreg;
      *(uint4*)&Vsm[cur ^ 1][srow][sc8] = vreg;
    }
    __syncthreads();
  }

  // ---- epilogue: vals[b, s, h*64+d] bf16 ----
  const int b = bh >> 3, h = bh & 7;
  #pragma unroll
  for (int reg = 0; reg < 16; reg++) {
    int qrow = (reg & 3) + 8 * (reg >> 2) + 4 * hi;
    float linv = 1.0f / __shfl(l, qrow);
    size_t grow = (size_t)(b * 1024 + q0 + wq * 32 + qrow) * 512 + h * 64;
    vals[grow + l31]      = f2bf(o[0][reg] * linv);
    vals[grow + 32 + l31] = f2bf(o[1][reg] * linv);
  }
}

// ------- LayerNorm: bf16 in (halved fetch), fp32 out ----------------------
__global__ void ln_norm3(const u16* __restrict__ ob, float* __restrict__ o,
                         const float2* __restrict__ partials) {
  const int blk = blockIdx.x;        // 2048 blocks; 256 per batch
  const int b = blk >> 8;
  const int lane = threadIdx.x & 63;
  float s1 = 0.f, s2 = 0.f;
  if (lane < 32) {
    float2 p = partials[b * 32 + lane];
    s1 = p.x; s2 = p.y;
  }
  #pragma unroll
  for (int off = 1; off < 64; off <<= 1) {
    s1 += __shfl_xor(s1, off);
    s2 += __shfl_xor(s2, off);
  }
  float mu = s1 / 524288.f;
  float rs = rsqrtf(s2 / 524288.f - mu * mu + 1e-5f);
  const size_t i = (size_t)blk * 2048 + threadIdx.x * 8;
  uint4 v = *(const uint4*)(ob + i);
  float4 o0, o1;
  o0.x = (bf2f((u16)(v.x & 0xffff)) - mu) * rs;
  o0.y = (bf2f((u16)(v.x >> 16)) - mu) * rs;
  o0.z = (bf2f((u16)(v.y & 0xffff)) - mu) * rs;
  o0.w = (bf2f((u16)(v.y >> 16)) - mu) * rs;
  o1.x = (bf2f((u16)(v.z & 0xffff)) - mu) * rs;
  o1.y = (bf2f((u16)(v.z >> 16)) - mu) * rs;
  o1.z = (bf2f((u16)(v.w & 0xffff)) - mu) * rs;
  o1.w = (bf2f((u16)(v.w >> 16)) - mu) * rs;
  *(float4*)(o + i) = o0;
  *(float4*)(o + i + 4) = o1;
}

extern "C" void kernel_launch(void* const* d_in, const int* in_sizes, int n_in,
                              void* d_out, int out_size, void* d_ws, size_t ws_size,
                              hipStream_t stream) {
  const float* x = (const float*)d_in[0];
  const float* wqkv = (const float*)d_in[1];
  const float* wo = (const float*)d_in[2];
  float* out = (float*)d_out;
  char* ws = (char*)d_ws;

  u16* xb        = (u16*)(ws + 0);          // 8192*512   bf16 =  8,388,608 B
  u16* wqb       = (u16*)(ws + 8388608);    // 1536*512   bf16 =  1,572,864 B
  u16* wob       = (u16*)(ws + 9961472);    // 512*512    bf16 =    524,288 B
  u16* qws       = (u16*)(ws + 10485760);   // [bh,1024,64]    =  8,388,608 B
  u16* kws       = (u16*)(ws + 18874368);   // [bh,1024,64]    =  8,388,608 B
  u16* vtws      = (u16*)(ws + 27262976);   // [bh,64,1024]    =  8,388,608 B
  u16* vals      = (u16*)(ws + 35651584);   // [8192,512] bf16 =  8,388,608 B
  u16* outb      = (u16*)(ws + 44040192);   // [8192,512] bf16 =  8,388,608 B
  float2* parts  = (float2*)(ws + 52428800);// 256 float2 = 2 KB

  cvt_all<<<1280, 256, 0, stream>>>(x, wqkv, wo, xb, wqb, wob);

  dim3 g1(64, 12);
  gemm_nt<0><<<g1, 256, 0, stream>>>(xb, wqb, 512, nullptr, qws, kws, vtws, nullptr);

  attn_kernel<<<256, 512, 0, stream>>>(qws, kws, vtws, vals);

  dim3 g2(64, 4);
  gemm_nt<1><<<g2, 256, 0, stream>>>(vals, wob, 512, outb, nullptr, nullptr, nullptr, parts);

  ln_norm3<<<2048, 256, 0, stream>>>(outb, out, parts);
}